// Round 1
// baseline (657.046 us; speedup 1.0000x reference)
//
#include <hip/hip_runtime.h>
#include <hip/hip_bf16.h>

#define NN 50000
#define EE 800000
#define GG 1024

// ---------------------------------------------------------------- degrees
__global__ __launch_bounds__(256) void k_deg(const int* __restrict__ dst,
                                             float* __restrict__ deg) {
    int i = blockIdx.x * 256 + threadIdx.x;
    if (i < EE) unsafeAtomicAdd(&deg[dst[i]], 1.0f);
}

__global__ __launch_bounds__(256) void k_dinv(const float* __restrict__ deg,
                                              float* __restrict__ dinv) {
    int i = blockIdx.x * 256 + threadIdx.x;
    if (i < NN) dinv[i] = rsqrtf(deg[i] + 1.0f);
}

// ---------------------------------------------------------------- GEMM 64x64, scaled by dinv[row]
// out hWs[row][c] = (sum_k h[row][k]*W[k][c]) * dinv[row]
__global__ __launch_bounds__(256) void k_gemm(const float* __restrict__ h,
                                              const float* __restrict__ W,
                                              const float* __restrict__ dinv,
                                              float* __restrict__ hWs, int n) {
    __shared__ float Wl[64 * 64];   // as float4 [64][16]
    __shared__ float hl[64 * 65];   // padded stride 65 -> conflict-free
    int tid  = threadIdx.x;
    int base = blockIdx.x * 64;

    const float4* Wg4 = (const float4*)W;
    float4* Wl4 = (float4*)Wl;
#pragma unroll
    for (int i = 0; i < 4; ++i) Wl4[tid + i * 256] = Wg4[tid + i * 256];

#pragma unroll
    for (int i = 0; i < 4; ++i) {
        int idx4 = tid + i * 256;       // float4 index into 64x64 tile
        int row  = idx4 >> 4;
        int c4   = idx4 & 15;
        float4 v = make_float4(0.f, 0.f, 0.f, 0.f);
        if (base + row < n) v = ((const float4*)h)[(size_t)(base + row) * 16 + c4];
        float* dp = &hl[row * 65 + c4 * 4];
        dp[0] = v.x; dp[1] = v.y; dp[2] = v.z; dp[3] = v.w;
    }
    __syncthreads();

    int col4 = tid & 15;   // 0..15 -> 4 output cols
    int rp   = tid >> 4;   // 0..15 -> rows rp, rp+16, rp+32, rp+48
    float4 a0 = make_float4(0, 0, 0, 0), a1 = a0, a2 = a0, a3 = a0;
    const float4* WlF4 = (const float4*)Wl;
#pragma unroll 8
    for (int k = 0; k < 64; ++k) {
        float4 w = WlF4[k * 16 + col4];
        float h0 = hl[rp * 65 + k];
        float h1 = hl[(rp + 16) * 65 + k];
        float h2 = hl[(rp + 32) * 65 + k];
        float h3 = hl[(rp + 48) * 65 + k];
        a0.x = fmaf(h0, w.x, a0.x); a0.y = fmaf(h0, w.y, a0.y); a0.z = fmaf(h0, w.z, a0.z); a0.w = fmaf(h0, w.w, a0.w);
        a1.x = fmaf(h1, w.x, a1.x); a1.y = fmaf(h1, w.y, a1.y); a1.z = fmaf(h1, w.z, a1.z); a1.w = fmaf(h1, w.w, a1.w);
        a2.x = fmaf(h2, w.x, a2.x); a2.y = fmaf(h2, w.y, a2.y); a2.z = fmaf(h2, w.z, a2.z); a2.w = fmaf(h2, w.w, a2.w);
        a3.x = fmaf(h3, w.x, a3.x); a3.y = fmaf(h3, w.y, a3.y); a3.z = fmaf(h3, w.z, a3.z); a3.w = fmaf(h3, w.w, a3.w);
    }
    float4 accs[4] = {a0, a1, a2, a3};
#pragma unroll
    for (int r = 0; r < 4; ++r) {
        int row = base + rp + 16 * r;
        if (row < n) {
            float s = dinv[row];
            float4 o = make_float4(accs[r].x * s, accs[r].y * s, accs[r].z * s, accs[r].w * s);
            ((float4*)hWs)[(size_t)row * 16 + col4] = o;
        }
    }
}

// ---------------------------------------------------------------- edge scatter: acc[dst] += hWs[src]
__global__ __launch_bounds__(256) void k_edge(const int* __restrict__ src,
                                              const int* __restrict__ dst,
                                              const float* __restrict__ hWs,
                                              float* __restrict__ acc,
                                              int ecount, int nwaves) {
    int gt   = blockIdx.x * 256 + threadIdx.x;
    int w    = gt >> 6;
    int lane = gt & 63;
    for (int e = w; e < ecount; e += nwaves) {
        int s = src[e];
        int d = dst[e];
        float v = hWs[(size_t)s * 64 + lane];
        unsafeAtomicAdd(&acc[(size_t)d * 64 + lane], v);
    }
}

// ---------------------------------------------------------------- finalize: h_out = relu(dinv*(acc+hWs)+b)
__global__ __launch_bounds__(256) void k_fin(const float* __restrict__ acc,
                                             const float* __restrict__ hWs,
                                             const float* __restrict__ dinv,
                                             const float* __restrict__ b,
                                             float* __restrict__ out) {
    int i4 = blockIdx.x * 256 + threadIdx.x;   // float4 index
    if (i4 >= NN * 16) return;
    int row = i4 >> 4;
    int c4  = i4 & 15;
    float s  = dinv[row];
    float4 a = ((const float4*)acc)[i4];
    float4 w = ((const float4*)hWs)[i4];
    float4 bb = ((const float4*)b)[c4];
    float4 o;
    o.x = fmaxf(fmaf(s, a.x + w.x, bb.x), 0.f);
    o.y = fmaxf(fmaf(s, a.y + w.y, bb.y), 0.f);
    o.z = fmaxf(fmaf(s, a.z + w.z, bb.z), 0.f);
    o.w = fmaxf(fmaf(s, a.w + w.w, bb.w), 0.f);
    ((float4*)out)[i4] = o;
}

// ---------------------------------------------------------------- pooling: g[batch[i]] += h[i]
__global__ __launch_bounds__(256) void k_pool(const int* __restrict__ batch,
                                              const float* __restrict__ h,
                                              float* __restrict__ g,
                                              int n, int nwaves) {
    int gt   = blockIdx.x * 256 + threadIdx.x;
    int w    = gt >> 6;
    int lane = gt & 63;
    for (int i = w; i < n; i += nwaves) {
        int b = batch[i];
        unsafeAtomicAdd(&g[(size_t)b * 64 + lane], h[(size_t)i * 64 + lane]);
    }
}

// ---------------------------------------------------------------- dense head, one block per graph
__global__ __launch_bounds__(256) void k_dense(const float* __restrict__ g,
                                               const float* __restrict__ Wd1, const float* __restrict__ bd1,
                                               const float* __restrict__ Wd2, const float* __restrict__ bd2,
                                               const float* __restrict__ Wa,  const float* __restrict__ ba,
                                               const float* __restrict__ temp,
                                               const float* __restrict__ mean,
                                               const float* __restrict__ stdv,
                                               float* __restrict__ out) {
    __shared__ float gl[64];
    __shared__ float d1[256];
    __shared__ float d2[128];
    __shared__ float coef[3];
    int tid = threadIdx.x;
    int gid = blockIdx.x;

    if (tid < 64) gl[tid] = fmaxf(g[(size_t)gid * 64 + tid], 0.f);
    __syncthreads();

    float a = bd1[tid];
#pragma unroll 8
    for (int k = 0; k < 64; ++k) a = fmaf(gl[k], Wd1[k * 256 + tid], a);
    d1[tid] = fmaxf(a, 0.f);
    __syncthreads();

    if (tid < 128) {
        float a2 = bd2[tid];
#pragma unroll 8
        for (int k = 0; k < 256; ++k) a2 = fmaf(d1[k], Wd2[k * 128 + tid], a2);
        d2[tid] = fmaxf(a2, 0.f);
    }
    __syncthreads();

    if (tid < 3) {
        float c = ba[tid];
        for (int k = 0; k < 128; ++k) c = fmaf(d2[k], Wa[k * 3 + tid], c);
        coef[tid] = c;
    }
    __syncthreads();

    if (tid == 0) {
        float A = coef[0], B = coef[1], C = coef[2];
        float T = temp[gid];
        float logP = A - B / (T + C);
        out[gid] = (logP - mean[0]) / stdv[0];
    }
}

// ----------------------------------------------------------------
extern "C" void kernel_launch(void* const* d_in, const int* in_sizes, int n_in,
                              void* d_out, int out_size, void* d_ws, size_t ws_size,
                              hipStream_t stream) {
    (void)in_sizes; (void)n_in; (void)out_size; (void)ws_size;
    const float* x     = (const float*)d_in[0];
    const int*   edges = (const int*)d_in[1];
    const int*   batch = (const int*)d_in[2];
    const float* temp  = (const float*)d_in[3];
    const float* mean  = (const float*)d_in[4];
    const float* stdv  = (const float*)d_in[5];
    const float* Wg1 = (const float*)d_in[6];  const float* bg1 = (const float*)d_in[7];
    const float* Wg2 = (const float*)d_in[8];  const float* bg2 = (const float*)d_in[9];
    const float* Wg3 = (const float*)d_in[10]; const float* bg3 = (const float*)d_in[11];
    const float* Wd1 = (const float*)d_in[12]; const float* bd1 = (const float*)d_in[13];
    const float* Wd2 = (const float*)d_in[14]; const float* bd2 = (const float*)d_in[15];
    const float* Wa  = (const float*)d_in[16]; const float* ba  = (const float*)d_in[17];

    float* ws   = (float*)d_ws;
    float* deg  = ws;                       // NN
    float* dinv = ws + NN;                  // NN
    float* bufA = ws + 2 * NN;              // NN*64
    float* bufB = bufA + (size_t)NN * 64;   // NN*64
    float* bufC = bufB + (size_t)NN * 64;   // NN*64
    float* gbuf = bufC + (size_t)NN * 64;   // GG*64

    const int* srcIdx = edges;
    const int* dstIdx = edges + EE;

    hipMemsetAsync(deg, 0, NN * sizeof(float), stream);
    k_deg<<<(EE + 255) / 256, 256, 0, stream>>>(dstIdx, deg);
    k_dinv<<<(NN + 255) / 256, 256, 0, stream>>>(deg, dinv);

    const int GEMM_BLOCKS = (NN + 63) / 64;
    const int EDGE_BLOCKS = 2048;
    const int FIN_BLOCKS  = (NN * 16 + 255) / 256;

    // ---- layer 1: in=x, hWs=bufB, acc/out=bufC
    k_gemm<<<GEMM_BLOCKS, 256, 0, stream>>>(x, Wg1, dinv, bufB, NN);
    hipMemsetAsync(bufC, 0, (size_t)NN * 64 * sizeof(float), stream);
    k_edge<<<EDGE_BLOCKS, 256, 0, stream>>>(srcIdx, dstIdx, bufB, bufC, EE, EDGE_BLOCKS * 4);
    k_fin<<<FIN_BLOCKS, 256, 0, stream>>>(bufC, bufB, dinv, bg1, bufC);

    // ---- layer 2: in=bufC, hWs=bufB, acc/out=bufA
    k_gemm<<<GEMM_BLOCKS, 256, 0, stream>>>(bufC, Wg2, dinv, bufB, NN);
    hipMemsetAsync(bufA, 0, (size_t)NN * 64 * sizeof(float), stream);
    k_edge<<<EDGE_BLOCKS, 256, 0, stream>>>(srcIdx, dstIdx, bufB, bufA, EE, EDGE_BLOCKS * 4);
    k_fin<<<FIN_BLOCKS, 256, 0, stream>>>(bufA, bufB, dinv, bg2, bufA);

    // ---- layer 3: in=bufA, hWs=bufB, acc/out=bufC
    k_gemm<<<GEMM_BLOCKS, 256, 0, stream>>>(bufA, Wg3, dinv, bufB, NN);
    hipMemsetAsync(bufC, 0, (size_t)NN * 64 * sizeof(float), stream);
    k_edge<<<EDGE_BLOCKS, 256, 0, stream>>>(srcIdx, dstIdx, bufB, bufC, EE, EDGE_BLOCKS * 4);
    k_fin<<<FIN_BLOCKS, 256, 0, stream>>>(bufC, bufB, dinv, bg3, bufC);

    // ---- pooling + head
    hipMemsetAsync(gbuf, 0, GG * 64 * sizeof(float), stream);
    k_pool<<<1024, 256, 0, stream>>>(batch, bufC, gbuf, NN, 1024 * 4);
    k_dense<<<GG, 256, 0, stream>>>(gbuf, Wd1, bd1, Wd2, bd2, Wa, ba, temp, mean, stdv, (float*)d_out);
}

// Round 2
// 366.886 us; speedup vs baseline: 1.7909x; 1.7909x over previous
//
#include <hip/hip_runtime.h>
#include <hip/hip_bf16.h>

#define NN 50000
#define EE 800000
#define GG 1024

// ---------------------------------------------------------------- dst histogram
__global__ __launch_bounds__(256) void k_count(const int* __restrict__ dst,
                                               int* __restrict__ cnt) {
    int i = blockIdx.x * 256 + threadIdx.x;
    if (i < EE) atomicAdd(&cnt[dst[i]], 1);
}

// ---------------------------------------------------------------- exclusive scan of cnt -> rowptr (one block)
__global__ __launch_bounds__(1024) void k_scan(const int* __restrict__ cnt,
                                               int* __restrict__ rowptr) {
    __shared__ int part[1024];
    int t = threadIdx.x;
    const int CH = (NN + 1023) / 1024;     // 49
    int beg = t * CH;
    int end = min(beg + CH, NN);
    int s = 0;
    for (int i = beg; i < end; ++i) s += cnt[i];
    part[t] = s;
    __syncthreads();
    int v = s;
    for (int off = 1; off < 1024; off <<= 1) {
        int add = (t >= off) ? part[t - off] : 0;
        __syncthreads();
        v += add;
        part[t] = v;
        __syncthreads();
    }
    int run = v - s;                       // exclusive prefix at chunk start
    for (int i = beg; i < end; ++i) { rowptr[i] = run; run += cnt[i]; }
    if (t == 1023) rowptr[NN] = part[1023];
}

// ---------------------------------------------------------------- fill CSR
__global__ __launch_bounds__(256) void k_fill(const int* __restrict__ src,
                                              const int* __restrict__ dst,
                                              const int* __restrict__ rowptr,
                                              int* __restrict__ cursor,
                                              int* __restrict__ csr_src) {
    int e = blockIdx.x * 256 + threadIdx.x;
    if (e < EE) {
        int d = dst[e];
        int slot = atomicAdd(&cursor[d], 1);
        csr_src[rowptr[d] + slot] = src[e];
    }
}

// ---------------------------------------------------------------- dinv
__global__ __launch_bounds__(256) void k_dinv(const int* __restrict__ cnt,
                                              float* __restrict__ dinv) {
    int i = blockIdx.x * 256 + threadIdx.x;
    if (i < NN) dinv[i] = rsqrtf((float)cnt[i] + 1.0f);
}

// ---------------------------------------------------------------- GEMM 64x64, scaled by dinv[row]
// hWs[row][c] = (sum_k h[row][k]*W[k][c]) * dinv[row]
__global__ __launch_bounds__(256) void k_gemm(const float* __restrict__ h,
                                              const float* __restrict__ W,
                                              const float* __restrict__ dinv,
                                              float* __restrict__ hWs, int n) {
    __shared__ float Wl[64 * 64];   // as float4 [64][16]
    __shared__ float hl[64 * 65];   // padded stride 65 -> conflict-free
    int tid  = threadIdx.x;
    int base = blockIdx.x * 64;

    const float4* Wg4 = (const float4*)W;
    float4* Wl4 = (float4*)Wl;
#pragma unroll
    for (int i = 0; i < 4; ++i) Wl4[tid + i * 256] = Wg4[tid + i * 256];

#pragma unroll
    for (int i = 0; i < 4; ++i) {
        int idx4 = tid + i * 256;       // float4 index into 64x64 tile
        int row  = idx4 >> 4;
        int c4   = idx4 & 15;
        float4 v = make_float4(0.f, 0.f, 0.f, 0.f);
        if (base + row < n) v = ((const float4*)h)[(size_t)(base + row) * 16 + c4];
        float* dp = &hl[row * 65 + c4 * 4];
        dp[0] = v.x; dp[1] = v.y; dp[2] = v.z; dp[3] = v.w;
    }
    __syncthreads();

    int col4 = tid & 15;   // 0..15 -> 4 output cols
    int rp   = tid >> 4;   // 0..15 -> rows rp, rp+16, rp+32, rp+48
    float4 a0 = make_float4(0, 0, 0, 0), a1 = a0, a2 = a0, a3 = a0;
    const float4* WlF4 = (const float4*)Wl;
#pragma unroll 8
    for (int k = 0; k < 64; ++k) {
        float4 w = WlF4[k * 16 + col4];
        float h0 = hl[rp * 65 + k];
        float h1 = hl[(rp + 16) * 65 + k];
        float h2 = hl[(rp + 32) * 65 + k];
        float h3 = hl[(rp + 48) * 65 + k];
        a0.x = fmaf(h0, w.x, a0.x); a0.y = fmaf(h0, w.y, a0.y); a0.z = fmaf(h0, w.z, a0.z); a0.w = fmaf(h0, w.w, a0.w);
        a1.x = fmaf(h1, w.x, a1.x); a1.y = fmaf(h1, w.y, a1.y); a1.z = fmaf(h1, w.z, a1.z); a1.w = fmaf(h1, w.w, a1.w);
        a2.x = fmaf(h2, w.x, a2.x); a2.y = fmaf(h2, w.y, a2.y); a2.z = fmaf(h2, w.z, a2.z); a2.w = fmaf(h2, w.w, a2.w);
        a3.x = fmaf(h3, w.x, a3.x); a3.y = fmaf(h3, w.y, a3.y); a3.z = fmaf(h3, w.z, a3.z); a3.w = fmaf(h3, w.w, a3.w);
    }
    float4 accs[4] = {a0, a1, a2, a3};
#pragma unroll
    for (int r = 0; r < 4; ++r) {
        int row = base + rp + 16 * r;
        if (row < n) {
            float s = dinv[row];
            float4 o = make_float4(accs[r].x * s, accs[r].y * s, accs[r].z * s, accs[r].w * s);
            ((float4*)hWs)[(size_t)row * 16 + col4] = o;
        }
    }
}

// ---------------------------------------------------------------- gather conv: one wave per node
// out[i] = relu(dinv[i] * (hWs[i] + sum_{e in(i)} hWs[csr_src[e]]) + b)
// optionally pool: g[batch[i]] += out[i]
template <bool POOL>
__global__ __launch_bounds__(256) void k_gather(const int* __restrict__ rowptr,
                                                const int* __restrict__ csr_src,
                                                const float* __restrict__ hWs,
                                                const float* __restrict__ dinv,
                                                const float* __restrict__ b,
                                                float* __restrict__ out,
                                                const int* __restrict__ batch,
                                                float* __restrict__ g) {
    int gt   = blockIdx.x * 256 + threadIdx.x;
    int i    = gt >> 6;
    int lane = gt & 63;
    if (i >= NN) return;

    float acc = hWs[i * 64 + lane];        // self term
    int e  = rowptr[i];
    int e1 = rowptr[i + 1];
    for (; e + 4 <= e1; e += 4) {
        int a0 = csr_src[e], a1 = csr_src[e + 1], a2 = csr_src[e + 2], a3 = csr_src[e + 3];
        float v0 = hWs[a0 * 64 + lane];
        float v1 = hWs[a1 * 64 + lane];
        float v2 = hWs[a2 * 64 + lane];
        float v3 = hWs[a3 * 64 + lane];
        acc += (v0 + v1) + (v2 + v3);
    }
    for (; e < e1; ++e) acc += hWs[csr_src[e] * 64 + lane];

    float o = fmaxf(fmaf(dinv[i], acc, b[lane]), 0.f);
    out[i * 64 + lane] = o;
    if (POOL) unsafeAtomicAdd(&g[batch[i] * 64 + lane], o);
}

// ---------------------------------------------------------------- dense head, one block per graph
__global__ __launch_bounds__(256) void k_dense(const float* __restrict__ g,
                                               const float* __restrict__ Wd1, const float* __restrict__ bd1,
                                               const float* __restrict__ Wd2, const float* __restrict__ bd2,
                                               const float* __restrict__ Wa,  const float* __restrict__ ba,
                                               const float* __restrict__ temp,
                                               const float* __restrict__ mean,
                                               const float* __restrict__ stdv,
                                               float* __restrict__ out) {
    __shared__ float gl[64];
    __shared__ float d1[256];
    __shared__ float d2[128];
    __shared__ float coef[3];
    int tid = threadIdx.x;
    int gid = blockIdx.x;

    if (tid < 64) gl[tid] = fmaxf(g[(size_t)gid * 64 + tid], 0.f);
    __syncthreads();

    float a = bd1[tid];
#pragma unroll 8
    for (int k = 0; k < 64; ++k) a = fmaf(gl[k], Wd1[k * 256 + tid], a);
    d1[tid] = fmaxf(a, 0.f);
    __syncthreads();

    if (tid < 128) {
        float a2 = bd2[tid];
#pragma unroll 8
        for (int k = 0; k < 256; ++k) a2 = fmaf(d1[k], Wd2[k * 128 + tid], a2);
        d2[tid] = fmaxf(a2, 0.f);
    }
    __syncthreads();

    if (tid < 3) {
        float c = ba[tid];
        for (int k = 0; k < 128; ++k) c = fmaf(d2[k], Wa[k * 3 + tid], c);
        coef[tid] = c;
    }
    __syncthreads();

    if (tid == 0) {
        float A = coef[0], B = coef[1], C = coef[2];
        float T = temp[gid];
        float logP = A - B / (T + C);
        out[gid] = (logP - mean[0]) / stdv[0];
    }
}

// ----------------------------------------------------------------
extern "C" void kernel_launch(void* const* d_in, const int* in_sizes, int n_in,
                              void* d_out, int out_size, void* d_ws, size_t ws_size,
                              hipStream_t stream) {
    (void)in_sizes; (void)n_in; (void)out_size; (void)ws_size;
    const float* x     = (const float*)d_in[0];
    const int*   edges = (const int*)d_in[1];
    const int*   batch = (const int*)d_in[2];
    const float* temp  = (const float*)d_in[3];
    const float* mean  = (const float*)d_in[4];
    const float* stdv  = (const float*)d_in[5];
    const float* Wg1 = (const float*)d_in[6];  const float* bg1 = (const float*)d_in[7];
    const float* Wg2 = (const float*)d_in[8];  const float* bg2 = (const float*)d_in[9];
    const float* Wg3 = (const float*)d_in[10]; const float* bg3 = (const float*)d_in[11];
    const float* Wd1 = (const float*)d_in[12]; const float* bd1 = (const float*)d_in[13];
    const float* Wd2 = (const float*)d_in[14]; const float* bd2 = (const float*)d_in[15];
    const float* Wa  = (const float*)d_in[16]; const float* ba  = (const float*)d_in[17];

    // ---- workspace layout
    char* wsb = (char*)d_ws;
    int*   cnt     = (int*)wsb;                          // NN
    int*   rowptr  = cnt + NN;                           // NN+1
    int*   cursor  = rowptr + NN + 1;                    // NN
    int*   csr_src = cursor + NN;                        // EE
    float* dinv    = (float*)(csr_src + EE);             // NN
    float* gbuf    = dinv + NN;                          // GG*64
    float* bufA    = gbuf + (size_t)GG * 64;             // NN*64
    float* bufB    = bufA + (size_t)NN * 64;             // NN*64

    const int* srcIdx = edges;
    const int* dstIdx = edges + EE;

    // ---- CSR build (once per launch)
    hipMemsetAsync(cnt, 0, NN * sizeof(int), stream);
    hipMemsetAsync(cursor, 0, NN * sizeof(int), stream);
    k_count<<<(EE + 255) / 256, 256, 0, stream>>>(dstIdx, cnt);
    k_scan<<<1, 1024, 0, stream>>>(cnt, rowptr);
    k_fill<<<(EE + 255) / 256, 256, 0, stream>>>(srcIdx, dstIdx, rowptr, cursor, csr_src);
    k_dinv<<<(NN + 255) / 256, 256, 0, stream>>>(cnt, dinv);

    const int GEMM_BLOCKS = (NN + 63) / 64;
    const int GATH_BLOCKS = (NN * 64 + 255) / 256;

    // ---- layer 1: x -> bufB(hWs) -> bufA
    k_gemm<<<GEMM_BLOCKS, 256, 0, stream>>>(x, Wg1, dinv, bufB, NN);
    k_gather<false><<<GATH_BLOCKS, 256, 0, stream>>>(rowptr, csr_src, bufB, dinv, bg1, bufA, batch, gbuf);

    // ---- layer 2: bufA -> bufB(hWs) -> bufA
    k_gemm<<<GEMM_BLOCKS, 256, 0, stream>>>(bufA, Wg2, dinv, bufB, NN);
    k_gather<false><<<GATH_BLOCKS, 256, 0, stream>>>(rowptr, csr_src, bufB, dinv, bg2, bufA, batch, gbuf);

    // ---- layer 3: bufA -> bufB(hWs) -> bufA, fused pooling into gbuf
    hipMemsetAsync(gbuf, 0, (size_t)GG * 64 * sizeof(float), stream);
    k_gemm<<<GEMM_BLOCKS, 256, 0, stream>>>(bufA, Wg3, dinv, bufB, NN);
    k_gather<true><<<GATH_BLOCKS, 256, 0, stream>>>(rowptr, csr_src, bufB, dinv, bg3, bufA, batch, gbuf);

    // ---- head
    k_dense<<<GG, 256, 0, stream>>>(gbuf, Wd1, bd1, Wd2, bd2, Wa, ba, temp, mean, stdv, (float*)d_out);
}

// Round 3
// 295.553 us; speedup vs baseline: 2.2231x; 1.2414x over previous
//
#include <hip/hip_runtime.h>
#include <hip/hip_bf16.h>

#define NN 50000
#define EE 800000
#define GG 1024
#define NB 196   // (NN+255)/256 scan blocks

// ---------------------------------------------------------------- dst histogram
__global__ __launch_bounds__(256) void k_count(const int* __restrict__ dst,
                                               int* __restrict__ cnt) {
    int i = blockIdx.x * 256 + threadIdx.x;
    if (i < EE) atomicAdd(&cnt[dst[i]], 1);
}

// ---------------------------------------------------------------- scan level 1: per-256 chunk
// writes local exclusive prefix to rowptr, block total to part, and dinv
__global__ __launch_bounds__(256) void k_scan1(const int* __restrict__ cnt,
                                               int* __restrict__ rowptr,
                                               int* __restrict__ part,
                                               float* __restrict__ dinv) {
    __shared__ int sh[256];
    int t = threadIdx.x;
    int i = blockIdx.x * 256 + t;
    int v = (i < NN) ? cnt[i] : 0;
    if (i < NN) dinv[i] = rsqrtf((float)v + 1.0f);
    sh[t] = v;
    __syncthreads();
    int acc = v;
    for (int off = 1; off < 256; off <<= 1) {
        int add = (t >= off) ? sh[t - off] : 0;
        __syncthreads();
        acc += add;
        sh[t] = acc;
        __syncthreads();
    }
    if (i < NN) rowptr[i] = acc - v;           // local exclusive prefix
    if (t == 255) part[blockIdx.x] = acc;      // block total
}

// ---------------------------------------------------------------- scan level 2: scan 196 block totals
__global__ __launch_bounds__(256) void k_scan2(int* __restrict__ part,
                                               int* __restrict__ partoff,
                                               int* __restrict__ rowptr) {
    __shared__ int sh[256];
    int t = threadIdx.x;
    int v = (t < NB) ? part[t] : 0;
    sh[t] = v;
    __syncthreads();
    int acc = v;
    for (int off = 1; off < 256; off <<= 1) {
        int add = (t >= off) ? sh[t - off] : 0;
        __syncthreads();
        acc += add;
        sh[t] = acc;
        __syncthreads();
    }
    if (t < NB) partoff[t] = acc - v;          // exclusive
    if (t == 255) rowptr[NN] = acc;            // total (== EE)
}

// ---------------------------------------------------------------- scan level 3: add block offsets
__global__ __launch_bounds__(256) void k_scan3(int* __restrict__ rowptr,
                                               const int* __restrict__ partoff) {
    int i = blockIdx.x * 256 + threadIdx.x;
    if (i < NN) rowptr[i] += partoff[blockIdx.x];
}

// ---------------------------------------------------------------- fill CSR (consumes cnt via atomicSub)
__global__ __launch_bounds__(256) void k_fill(const int* __restrict__ src,
                                              const int* __restrict__ dst,
                                              const int* __restrict__ rowptr,
                                              int* __restrict__ cnt,
                                              int* __restrict__ csr_src) {
    int e = blockIdx.x * 256 + threadIdx.x;
    if (e < EE) {
        int d = dst[e];
        int slot = atomicSub(&cnt[d], 1) - 1;
        csr_src[rowptr[d] + slot] = src[e];
    }
}

// ---------------------------------------------------------------- GEMM 64x64, scaled by dinv[row]
// hWs[row][c] = (sum_k h[row][k]*W[k][c]) * dinv[row]
__global__ __launch_bounds__(256) void k_gemm(const float* __restrict__ h,
                                              const float* __restrict__ W,
                                              const float* __restrict__ dinv,
                                              float* __restrict__ hWs, int n) {
    __shared__ float Wl[64 * 64];   // as float4 [64][16]
    __shared__ float hl[64 * 65];   // padded stride 65 -> conflict-free
    int tid  = threadIdx.x;
    int base = blockIdx.x * 64;

    const float4* Wg4 = (const float4*)W;
    float4* Wl4 = (float4*)Wl;
#pragma unroll
    for (int i = 0; i < 4; ++i) Wl4[tid + i * 256] = Wg4[tid + i * 256];

#pragma unroll
    for (int i = 0; i < 4; ++i) {
        int idx4 = tid + i * 256;       // float4 index into 64x64 tile
        int row  = idx4 >> 4;
        int c4   = idx4 & 15;
        float4 v = make_float4(0.f, 0.f, 0.f, 0.f);
        if (base + row < n) v = ((const float4*)h)[(size_t)(base + row) * 16 + c4];
        float* dp = &hl[row * 65 + c4 * 4];
        dp[0] = v.x; dp[1] = v.y; dp[2] = v.z; dp[3] = v.w;
    }
    __syncthreads();

    int col4 = tid & 15;   // 0..15 -> 4 output cols
    int rp   = tid >> 4;   // 0..15 -> rows rp, rp+16, rp+32, rp+48
    float4 a0 = make_float4(0, 0, 0, 0), a1 = a0, a2 = a0, a3 = a0;
    const float4* WlF4 = (const float4*)Wl;
#pragma unroll 8
    for (int k = 0; k < 64; ++k) {
        float4 w = WlF4[k * 16 + col4];
        float h0 = hl[rp * 65 + k];
        float h1 = hl[(rp + 16) * 65 + k];
        float h2 = hl[(rp + 32) * 65 + k];
        float h3 = hl[(rp + 48) * 65 + k];
        a0.x = fmaf(h0, w.x, a0.x); a0.y = fmaf(h0, w.y, a0.y); a0.z = fmaf(h0, w.z, a0.z); a0.w = fmaf(h0, w.w, a0.w);
        a1.x = fmaf(h1, w.x, a1.x); a1.y = fmaf(h1, w.y, a1.y); a1.z = fmaf(h1, w.z, a1.z); a1.w = fmaf(h1, w.w, a1.w);
        a2.x = fmaf(h2, w.x, a2.x); a2.y = fmaf(h2, w.y, a2.y); a2.z = fmaf(h2, w.z, a2.z); a2.w = fmaf(h2, w.w, a2.w);
        a3.x = fmaf(h3, w.x, a3.x); a3.y = fmaf(h3, w.y, a3.y); a3.z = fmaf(h3, w.z, a3.z); a3.w = fmaf(h3, w.w, a3.w);
    }
    float4 accs[4] = {a0, a1, a2, a3};
#pragma unroll
    for (int r = 0; r < 4; ++r) {
        int row = base + rp + 16 * r;
        if (row < n) {
            float s = dinv[row];
            float4 o = make_float4(accs[r].x * s, accs[r].y * s, accs[r].z * s, accs[r].w * s);
            ((float4*)hWs)[(size_t)row * 16 + col4] = o;
        }
    }
}

// ---------------------------------------------------------------- gather conv: one wave per node
// out[i] = relu(dinv[i] * (hWs[i] + sum_{e in(i)} hWs[csr_src[e]]) + b)
// optionally pool: g[batch[i]] += out[i]
template <bool POOL>
__global__ __launch_bounds__(256) void k_gather(const int* __restrict__ rowptr,
                                                const int* __restrict__ csr_src,
                                                const float* __restrict__ hWs,
                                                const float* __restrict__ dinv,
                                                const float* __restrict__ b,
                                                float* __restrict__ out,
                                                const int* __restrict__ batch,
                                                float* __restrict__ g) {
    int gt   = blockIdx.x * 256 + threadIdx.x;
    int i    = gt >> 6;
    int lane = gt & 63;
    if (i >= NN) return;

    float acc = hWs[i * 64 + lane];        // self term
    int e  = rowptr[i];
    int e1 = rowptr[i + 1];
    for (; e + 4 <= e1; e += 4) {
        int a0 = csr_src[e], a1 = csr_src[e + 1], a2 = csr_src[e + 2], a3 = csr_src[e + 3];
        float v0 = hWs[a0 * 64 + lane];
        float v1 = hWs[a1 * 64 + lane];
        float v2 = hWs[a2 * 64 + lane];
        float v3 = hWs[a3 * 64 + lane];
        acc += (v0 + v1) + (v2 + v3);
    }
    for (; e < e1; ++e) acc += hWs[csr_src[e] * 64 + lane];

    float o = fmaxf(fmaf(dinv[i], acc, b[lane]), 0.f);
    out[i * 64 + lane] = o;
    if (POOL) unsafeAtomicAdd(&g[batch[i] * 64 + lane], o);
}

// ---------------------------------------------------------------- dense head, one block per graph
__global__ __launch_bounds__(256) void k_dense(const float* __restrict__ g,
                                               const float* __restrict__ Wd1, const float* __restrict__ bd1,
                                               const float* __restrict__ Wd2, const float* __restrict__ bd2,
                                               const float* __restrict__ Wa,  const float* __restrict__ ba,
                                               const float* __restrict__ temp,
                                               const float* __restrict__ mean,
                                               const float* __restrict__ stdv,
                                               float* __restrict__ out) {
    __shared__ float gl[64];
    __shared__ float d1[256];
    __shared__ float d2[128];
    __shared__ float coef[3];
    int tid = threadIdx.x;
    int gid = blockIdx.x;

    if (tid < 64) gl[tid] = fmaxf(g[(size_t)gid * 64 + tid], 0.f);
    __syncthreads();

    float a = bd1[tid];
#pragma unroll 8
    for (int k = 0; k < 64; ++k) a = fmaf(gl[k], Wd1[k * 256 + tid], a);
    d1[tid] = fmaxf(a, 0.f);
    __syncthreads();

    if (tid < 128) {
        float a2 = bd2[tid];
#pragma unroll 8
        for (int k = 0; k < 256; ++k) a2 = fmaf(d1[k], Wd2[k * 128 + tid], a2);
        d2[tid] = fmaxf(a2, 0.f);
    }
    __syncthreads();

    if (tid < 3) {
        float c = ba[tid];
        for (int k = 0; k < 128; ++k) c = fmaf(d2[k], Wa[k * 3 + tid], c);
        coef[tid] = c;
    }
    __syncthreads();

    if (tid == 0) {
        float A = coef[0], B = coef[1], C = coef[2];
        float T = temp[gid];
        float logP = A - B / (T + C);
        out[gid] = (logP - mean[0]) / stdv[0];
    }
}

// ----------------------------------------------------------------
extern "C" void kernel_launch(void* const* d_in, const int* in_sizes, int n_in,
                              void* d_out, int out_size, void* d_ws, size_t ws_size,
                              hipStream_t stream) {
    (void)in_sizes; (void)n_in; (void)out_size; (void)ws_size;
    const float* x     = (const float*)d_in[0];
    const int*   edges = (const int*)d_in[1];
    const int*   batch = (const int*)d_in[2];
    const float* temp  = (const float*)d_in[3];
    const float* mean  = (const float*)d_in[4];
    const float* stdv  = (const float*)d_in[5];
    const float* Wg1 = (const float*)d_in[6];  const float* bg1 = (const float*)d_in[7];
    const float* Wg2 = (const float*)d_in[8];  const float* bg2 = (const float*)d_in[9];
    const float* Wg3 = (const float*)d_in[10]; const float* bg3 = (const float*)d_in[11];
    const float* Wd1 = (const float*)d_in[12]; const float* bd1 = (const float*)d_in[13];
    const float* Wd2 = (const float*)d_in[14]; const float* bd2 = (const float*)d_in[15];
    const float* Wa  = (const float*)d_in[16]; const float* ba  = (const float*)d_in[17];

    // ---- workspace layout
    char* wsb = (char*)d_ws;
    int*   cnt     = (int*)wsb;                          // NN
    int*   rowptr  = cnt + NN;                           // NN+1
    int*   part    = rowptr + NN + 1;                    // NB
    int*   partoff = part + NB;                          // NB
    int*   csr_src = partoff + NB;                       // EE
    float* dinv    = (float*)(csr_src + EE);             // NN
    float* gbuf    = dinv + NN;                          // GG*64
    float* bufA    = gbuf + (size_t)GG * 64;             // NN*64
    float* bufB    = bufA + (size_t)NN * 64;             // NN*64

    const int* srcIdx = edges;
    const int* dstIdx = edges + EE;

    // ---- CSR build (once per launch)
    hipMemsetAsync(cnt, 0, NN * sizeof(int), stream);
    k_count<<<(EE + 255) / 256, 256, 0, stream>>>(dstIdx, cnt);
    k_scan1<<<NB, 256, 0, stream>>>(cnt, rowptr, part, dinv);
    k_scan2<<<1, 256, 0, stream>>>(part, partoff, rowptr);
    k_scan3<<<NB, 256, 0, stream>>>(rowptr, partoff);
    k_fill<<<(EE + 255) / 256, 256, 0, stream>>>(srcIdx, dstIdx, rowptr, cnt, csr_src);

    const int GEMM_BLOCKS = (NN + 63) / 64;
    const int GATH_BLOCKS = (NN * 64 + 255) / 256;

    // ---- layer 1: x -> bufB(hWs) -> bufA
    k_gemm<<<GEMM_BLOCKS, 256, 0, stream>>>(x, Wg1, dinv, bufB, NN);
    k_gather<false><<<GATH_BLOCKS, 256, 0, stream>>>(rowptr, csr_src, bufB, dinv, bg1, bufA, batch, gbuf);

    // ---- layer 2: bufA -> bufB(hWs) -> bufA
    k_gemm<<<GEMM_BLOCKS, 256, 0, stream>>>(bufA, Wg2, dinv, bufB, NN);
    k_gather<false><<<GATH_BLOCKS, 256, 0, stream>>>(rowptr, csr_src, bufB, dinv, bg2, bufA, batch, gbuf);

    // ---- layer 3: bufA -> bufB(hWs) -> bufA, fused pooling into gbuf
    hipMemsetAsync(gbuf, 0, (size_t)GG * 64 * sizeof(float), stream);
    k_gemm<<<GEMM_BLOCKS, 256, 0, stream>>>(bufA, Wg3, dinv, bufB, NN);
    k_gather<true><<<GATH_BLOCKS, 256, 0, stream>>>(rowptr, csr_src, bufB, dinv, bg3, bufA, batch, gbuf);

    // ---- head
    k_dense<<<GG, 256, 0, stream>>>(gbuf, Wd1, bd1, Wd2, bd2, Wa, ba, temp, mean, stdv, (float*)d_out);
}

// Round 4
// 288.531 us; speedup vs baseline: 2.2772x; 1.0243x over previous
//
#include <hip/hip_runtime.h>
#include <hip/hip_bf16.h>

#define NN 50000
#define EE 800000
#define GG 1024
#define NB 196   // (NN+255)/256 scan blocks

// ---- bf16x2 helpers (packed in a uint: lo half = even feature, hi = odd)
__device__ __forceinline__ float blo(unsigned u) { return __uint_as_float(u << 16); }
__device__ __forceinline__ float bhi(unsigned u) { return __uint_as_float(u & 0xffff0000u); }
__device__ __forceinline__ unsigned packbf(float a, float b) {
    unsigned ua = __float_as_uint(a); ua += 0x7fffu + ((ua >> 16) & 1u);
    unsigned ub = __float_as_uint(b); ub += 0x7fffu + ((ub >> 16) & 1u);
    return (ua >> 16) | (ub & 0xffff0000u);
}

// ---------------------------------------------------------------- dst histogram
__global__ __launch_bounds__(256) void k_count(const int* __restrict__ dst,
                                               int* __restrict__ cnt) {
    int i = blockIdx.x * 256 + threadIdx.x;
    if (i < EE) atomicAdd(&cnt[dst[i]], 1);
}

// ---------------------------------------------------------------- scan level 1
__global__ __launch_bounds__(256) void k_scan1(const int* __restrict__ cnt,
                                               int* __restrict__ rowptr,
                                               int* __restrict__ part,
                                               float* __restrict__ dinv) {
    __shared__ int sh[256];
    int t = threadIdx.x;
    int i = blockIdx.x * 256 + t;
    int v = (i < NN) ? cnt[i] : 0;
    if (i < NN) dinv[i] = rsqrtf((float)v + 1.0f);
    sh[t] = v;
    __syncthreads();
    int acc = v;
    for (int off = 1; off < 256; off <<= 1) {
        int add = (t >= off) ? sh[t - off] : 0;
        __syncthreads();
        acc += add;
        sh[t] = acc;
        __syncthreads();
    }
    if (i < NN) rowptr[i] = acc - v;
    if (t == 255) part[blockIdx.x] = acc;
}

// ---------------------------------------------------------------- scan level 2
__global__ __launch_bounds__(256) void k_scan2(int* __restrict__ part,
                                               int* __restrict__ partoff,
                                               int* __restrict__ rowptr) {
    __shared__ int sh[256];
    int t = threadIdx.x;
    int v = (t < NB) ? part[t] : 0;
    sh[t] = v;
    __syncthreads();
    int acc = v;
    for (int off = 1; off < 256; off <<= 1) {
        int add = (t >= off) ? sh[t - off] : 0;
        __syncthreads();
        acc += add;
        sh[t] = acc;
        __syncthreads();
    }
    if (t < NB) partoff[t] = acc - v;
    if (t == 255) rowptr[NN] = acc;
}

// ---------------------------------------------------------------- scan level 3
__global__ __launch_bounds__(256) void k_scan3(int* __restrict__ rowptr,
                                               const int* __restrict__ partoff) {
    int i = blockIdx.x * 256 + threadIdx.x;
    if (i < NN) rowptr[i] += partoff[blockIdx.x];
}

// ---------------------------------------------------------------- fill CSR
__global__ __launch_bounds__(256) void k_fill(const int* __restrict__ src,
                                              const int* __restrict__ dst,
                                              const int* __restrict__ rowptr,
                                              int* __restrict__ cnt,
                                              int* __restrict__ csr_src) {
    int e = blockIdx.x * 256 + threadIdx.x;
    if (e < EE) {
        int d = dst[e];
        int slot = atomicSub(&cnt[d], 1) - 1;
        csr_src[rowptr[d] + slot] = src[e];
    }
}

// ---------------------------------------------------------------- GEMM 64x64, scaled by dinv[row], bf16 out
// hWs[row][c] = (sum_k h[row][k]*W[k][c]) * dinv[row]
template <bool BF16IN>
__global__ __launch_bounds__(256) void k_gemm(const void* __restrict__ hv,
                                              const float* __restrict__ W,
                                              const float* __restrict__ dinv,
                                              unsigned* __restrict__ hWs, int n) {
    __shared__ float Wl[64 * 64];   // as float4 [64][16]
    __shared__ float hl[64 * 65];   // padded stride 65
    int tid  = threadIdx.x;
    int base = blockIdx.x * 64;

    const float4* Wg4 = (const float4*)W;
    float4* Wl4 = (float4*)Wl;
#pragma unroll
    for (int i = 0; i < 4; ++i) Wl4[tid + i * 256] = Wg4[tid + i * 256];

    if (BF16IN) {
        const unsigned* hb = (const unsigned*)hv;
#pragma unroll
        for (int i = 0; i < 8; ++i) {
            int idx = tid + i * 256;        // uint index in 64x32 tile
            int row = idx >> 5;
            int pc  = idx & 31;
            unsigned v = (base + row < n) ? hb[(size_t)(base + row) * 32 + pc] : 0u;
            hl[row * 65 + 2 * pc]     = blo(v);
            hl[row * 65 + 2 * pc + 1] = bhi(v);
        }
    } else {
        const float4* hg = (const float4*)hv;
#pragma unroll
        for (int i = 0; i < 4; ++i) {
            int idx4 = tid + i * 256;
            int row  = idx4 >> 4;
            int c4   = idx4 & 15;
            float4 v = make_float4(0.f, 0.f, 0.f, 0.f);
            if (base + row < n) v = hg[(size_t)(base + row) * 16 + c4];
            float* dp = &hl[row * 65 + c4 * 4];
            dp[0] = v.x; dp[1] = v.y; dp[2] = v.z; dp[3] = v.w;
        }
    }
    __syncthreads();

    int col4 = tid & 15;
    int rp   = tid >> 4;
    float4 a0 = make_float4(0, 0, 0, 0), a1 = a0, a2 = a0, a3 = a0;
    const float4* WlF4 = (const float4*)Wl;
#pragma unroll 8
    for (int k = 0; k < 64; ++k) {
        float4 w = WlF4[k * 16 + col4];
        float h0 = hl[rp * 65 + k];
        float h1 = hl[(rp + 16) * 65 + k];
        float h2 = hl[(rp + 32) * 65 + k];
        float h3 = hl[(rp + 48) * 65 + k];
        a0.x = fmaf(h0, w.x, a0.x); a0.y = fmaf(h0, w.y, a0.y); a0.z = fmaf(h0, w.z, a0.z); a0.w = fmaf(h0, w.w, a0.w);
        a1.x = fmaf(h1, w.x, a1.x); a1.y = fmaf(h1, w.y, a1.y); a1.z = fmaf(h1, w.z, a1.z); a1.w = fmaf(h1, w.w, a1.w);
        a2.x = fmaf(h2, w.x, a2.x); a2.y = fmaf(h2, w.y, a2.y); a2.z = fmaf(h2, w.z, a2.z); a2.w = fmaf(h2, w.w, a2.w);
        a3.x = fmaf(h3, w.x, a3.x); a3.y = fmaf(h3, w.y, a3.y); a3.z = fmaf(h3, w.z, a3.z); a3.w = fmaf(h3, w.w, a3.w);
    }
    float4 accs[4] = {a0, a1, a2, a3};
#pragma unroll
    for (int r = 0; r < 4; ++r) {
        int row = base + rp + 16 * r;
        if (row < n) {
            float s = dinv[row];
            ((uint2*)hWs)[(size_t)row * 16 + col4] =
                make_uint2(packbf(accs[r].x * s, accs[r].y * s),
                           packbf(accs[r].z * s, accs[r].w * s));
        }
    }
}

// ---------------------------------------------------------------- gather conv (bf16): 32 lanes per node, lane = feature pair
// out[i] = relu(dinv[i] * (hWs[i] + sum_in hWs[src]) + b);  POOL: g[batch[i]] += out (no feature write)
template <bool POOL>
__global__ __launch_bounds__(256) void k_gather(const int* __restrict__ rowptr,
                                                const int* __restrict__ csr_src,
                                                const unsigned* __restrict__ hWs,
                                                const float* __restrict__ dinv,
                                                const float* __restrict__ bias,
                                                unsigned* __restrict__ out,
                                                const int* __restrict__ batch,
                                                float* __restrict__ g) {
    int gt = blockIdx.x * 256 + threadIdx.x;
    int i  = gt >> 5;
    int p  = gt & 31;
    if (i >= NN) return;

    unsigned self = hWs[(size_t)i * 32 + p];
    float acc0 = blo(self), acc1 = bhi(self);
    int e  = rowptr[i];
    int e1 = rowptr[i + 1];
    for (; e + 4 <= e1; e += 4) {
        int a0 = csr_src[e], a1 = csr_src[e + 1], a2 = csr_src[e + 2], a3 = csr_src[e + 3];
        unsigned v0 = hWs[(size_t)a0 * 32 + p];
        unsigned v1 = hWs[(size_t)a1 * 32 + p];
        unsigned v2 = hWs[(size_t)a2 * 32 + p];
        unsigned v3 = hWs[(size_t)a3 * 32 + p];
        acc0 += (blo(v0) + blo(v1)) + (blo(v2) + blo(v3));
        acc1 += (bhi(v0) + bhi(v1)) + (bhi(v2) + bhi(v3));
    }
    for (; e < e1; ++e) {
        unsigned v = hWs[(size_t)csr_src[e] * 32 + p];
        acc0 += blo(v); acc1 += bhi(v);
    }

    float d  = dinv[i];
    float o0 = fmaxf(fmaf(d, acc0, bias[2 * p]), 0.f);
    float o1 = fmaxf(fmaf(d, acc1, bias[2 * p + 1]), 0.f);
    if (POOL) {
        int bg = batch[i];
        unsafeAtomicAdd(&g[(size_t)bg * 64 + 2 * p],     o0);
        unsafeAtomicAdd(&g[(size_t)bg * 64 + 2 * p + 1], o1);
    } else {
        out[(size_t)i * 32 + p] = packbf(o0, o1);
    }
}

// ---------------------------------------------------------------- dense head, one block per graph
__global__ __launch_bounds__(256) void k_dense(const float* __restrict__ g,
                                               const float* __restrict__ Wd1, const float* __restrict__ bd1,
                                               const float* __restrict__ Wd2, const float* __restrict__ bd2,
                                               const float* __restrict__ Wa,  const float* __restrict__ ba,
                                               const float* __restrict__ temp,
                                               const float* __restrict__ mean,
                                               const float* __restrict__ stdv,
                                               float* __restrict__ out) {
    __shared__ float gl[64];
    __shared__ float d1[256];
    __shared__ float d2[128];
    __shared__ float coef[3];
    int tid = threadIdx.x;
    int gid = blockIdx.x;

    if (tid < 64) gl[tid] = fmaxf(g[(size_t)gid * 64 + tid], 0.f);
    __syncthreads();

    float a = bd1[tid];
#pragma unroll 8
    for (int k = 0; k < 64; ++k) a = fmaf(gl[k], Wd1[k * 256 + tid], a);
    d1[tid] = fmaxf(a, 0.f);
    __syncthreads();

    if (tid < 128) {
        float a2 = bd2[tid];
#pragma unroll 8
        for (int k = 0; k < 256; ++k) a2 = fmaf(d1[k], Wd2[k * 128 + tid], a2);
        d2[tid] = fmaxf(a2, 0.f);
    }
    __syncthreads();

    if (tid < 3) {
        float c = ba[tid];
        for (int k = 0; k < 128; ++k) c = fmaf(d2[k], Wa[k * 3 + tid], c);
        coef[tid] = c;
    }
    __syncthreads();

    if (tid == 0) {
        float A = coef[0], B = coef[1], C = coef[2];
        float T = temp[gid];
        float logP = A - B / (T + C);
        out[gid] = (logP - mean[0]) / stdv[0];
    }
}

// ----------------------------------------------------------------
extern "C" void kernel_launch(void* const* d_in, const int* in_sizes, int n_in,
                              void* d_out, int out_size, void* d_ws, size_t ws_size,
                              hipStream_t stream) {
    (void)in_sizes; (void)n_in; (void)out_size; (void)ws_size;
    const float* x     = (const float*)d_in[0];
    const int*   edges = (const int*)d_in[1];
    const int*   batch = (const int*)d_in[2];
    const float* temp  = (const float*)d_in[3];
    const float* mean  = (const float*)d_in[4];
    const float* stdv  = (const float*)d_in[5];
    const float* Wg1 = (const float*)d_in[6];  const float* bg1 = (const float*)d_in[7];
    const float* Wg2 = (const float*)d_in[8];  const float* bg2 = (const float*)d_in[9];
    const float* Wg3 = (const float*)d_in[10]; const float* bg3 = (const float*)d_in[11];
    const float* Wd1 = (const float*)d_in[12]; const float* bd1 = (const float*)d_in[13];
    const float* Wd2 = (const float*)d_in[14]; const float* bd2 = (const float*)d_in[15];
    const float* Wa  = (const float*)d_in[16]; const float* ba  = (const float*)d_in[17];

    // ---- workspace layout
    char* wsb = (char*)d_ws;
    int*      cnt     = (int*)wsb;                       // NN
    int*      rowptr  = cnt + NN;                        // NN+1
    int*      part    = rowptr + NN + 1;                 // NB
    int*      partoff = part + NB;                       // NB
    int*      csr_src = partoff + NB;                    // EE
    float*    dinv    = (float*)(csr_src + EE);          // NN
    float*    gbuf    = dinv + NN;                       // GG*64
    unsigned* bufA    = (unsigned*)(gbuf + (size_t)GG * 64);  // NN*32 (bf16x2)
    unsigned* bufB    = bufA + (size_t)NN * 32;               // NN*32 (bf16x2)

    const int* srcIdx = edges;
    const int* dstIdx = edges + EE;

    // ---- CSR build
    hipMemsetAsync(cnt, 0, NN * sizeof(int), stream);
    k_count<<<(EE + 255) / 256, 256, 0, stream>>>(dstIdx, cnt);
    k_scan1<<<NB, 256, 0, stream>>>(cnt, rowptr, part, dinv);
    k_scan2<<<1, 256, 0, stream>>>(part, partoff, rowptr);
    k_scan3<<<NB, 256, 0, stream>>>(rowptr, partoff);
    k_fill<<<(EE + 255) / 256, 256, 0, stream>>>(srcIdx, dstIdx, rowptr, cnt, csr_src);

    const int GEMM_BLOCKS = (NN + 63) / 64;
    const int GATH_BLOCKS = (NN * 32 + 255) / 256;

    // ---- layer 1: x(fp32) -> bufB(hWs bf16) -> bufA(bf16)
    k_gemm<false><<<GEMM_BLOCKS, 256, 0, stream>>>(x, Wg1, dinv, bufB, NN);
    k_gather<false><<<GATH_BLOCKS, 256, 0, stream>>>(rowptr, csr_src, bufB, dinv, bg1, bufA, batch, gbuf);

    // ---- layer 2: bufA -> bufB -> bufA
    k_gemm<true><<<GEMM_BLOCKS, 256, 0, stream>>>(bufA, Wg2, dinv, bufB, NN);
    k_gather<false><<<GATH_BLOCKS, 256, 0, stream>>>(rowptr, csr_src, bufB, dinv, bg2, bufA, batch, gbuf);

    // ---- layer 3: bufA -> bufB -> pool into gbuf (no feature write)
    hipMemsetAsync(gbuf, 0, (size_t)GG * 64 * sizeof(float), stream);
    k_gemm<true><<<GEMM_BLOCKS, 256, 0, stream>>>(bufA, Wg3, dinv, bufB, NN);
    k_gather<true><<<GATH_BLOCKS, 256, 0, stream>>>(rowptr, csr_src, bufB, dinv, bg3, bufA, batch, gbuf);

    // ---- head
    k_dense<<<GG, 256, 0, stream>>>(gbuf, Wd1, bd1, Wd2, bd2, Wa, ba, temp, mean, stdv, (float*)d_out);
}

// Round 5
// 271.215 us; speedup vs baseline: 2.4226x; 1.0638x over previous
//
#include <hip/hip_runtime.h>
#include <hip/hip_bf16.h>

#define NN 50000
#define EE 800000
#define GG 1024
#define NB 196   // (NN+255)/256 scan blocks

// ---- bf16x2 helpers (packed in a uint: lo half = even feature, hi = odd)
__device__ __forceinline__ float blo(unsigned u) { return __uint_as_float(u << 16); }
__device__ __forceinline__ float bhi(unsigned u) { return __uint_as_float(u & 0xffff0000u); }
__device__ __forceinline__ unsigned packbf(float a, float b) {
    unsigned ua = __float_as_uint(a); ua += 0x7fffu + ((ua >> 16) & 1u);
    unsigned ub = __float_as_uint(b); ub += 0x7fffu + ((ub >> 16) & 1u);
    return (ua >> 16) | (ub & 0xffff0000u);
}

// ---------------------------------------------------------------- dst histogram
__global__ __launch_bounds__(256) void k_count(const int* __restrict__ dst,
                                               int* __restrict__ cnt) {
    int i = blockIdx.x * 256 + threadIdx.x;
    if (i < EE) atomicAdd(&cnt[dst[i]], 1);
}

// ---------------------------------------------------------------- scan level 1
__global__ __launch_bounds__(256) void k_scan1(const int* __restrict__ cnt,
                                               int* __restrict__ rowptr,
                                               int* __restrict__ part,
                                               float* __restrict__ dinv) {
    __shared__ int sh[256];
    int t = threadIdx.x;
    int i = blockIdx.x * 256 + t;
    int v = (i < NN) ? cnt[i] : 0;
    if (i < NN) dinv[i] = rsqrtf((float)v + 1.0f);
    sh[t] = v;
    __syncthreads();
    int acc = v;
    for (int off = 1; off < 256; off <<= 1) {
        int add = (t >= off) ? sh[t - off] : 0;
        __syncthreads();
        acc += add;
        sh[t] = acc;
        __syncthreads();
    }
    if (i < NN) rowptr[i] = acc - v;
    if (t == 255) part[blockIdx.x] = acc;
}

// ---------------------------------------------------------------- scan level 2
__global__ __launch_bounds__(256) void k_scan2(int* __restrict__ part,
                                               int* __restrict__ partoff,
                                               int* __restrict__ rowptr) {
    __shared__ int sh[256];
    int t = threadIdx.x;
    int v = (t < NB) ? part[t] : 0;
    sh[t] = v;
    __syncthreads();
    int acc = v;
    for (int off = 1; off < 256; off <<= 1) {
        int add = (t >= off) ? sh[t - off] : 0;
        __syncthreads();
        acc += add;
        sh[t] = acc;
        __syncthreads();
    }
    if (t < NB) partoff[t] = acc - v;
    if (t == 255) rowptr[NN] = acc;
}

// ---------------------------------------------------------------- scan level 3
__global__ __launch_bounds__(256) void k_scan3(int* __restrict__ rowptr,
                                               const int* __restrict__ partoff) {
    int i = blockIdx.x * 256 + threadIdx.x;
    if (i < NN) rowptr[i] += partoff[blockIdx.x];
}

// ---------------------------------------------------------------- fill CSR
__global__ __launch_bounds__(256) void k_fill(const int* __restrict__ src,
                                              const int* __restrict__ dst,
                                              const int* __restrict__ rowptr,
                                              int* __restrict__ cnt,
                                              int* __restrict__ csr_src) {
    int e = blockIdx.x * 256 + threadIdx.x;
    if (e < EE) {
        int d = dst[e];
        int slot = atomicSub(&cnt[d], 1) - 1;
        csr_src[rowptr[d] + slot] = src[e];
    }
}

// ---------------------------------------------------------------- GEMM 64x64, scaled by dinv[row], bf16 out
template <bool BF16IN>
__global__ __launch_bounds__(256) void k_gemm(const void* __restrict__ hv,
                                              const float* __restrict__ W,
                                              const float* __restrict__ dinv,
                                              unsigned* __restrict__ hWs, int n) {
    __shared__ float Wl[64 * 64];   // as float4 [64][16]
    __shared__ float hl[64 * 65];   // padded stride 65
    int tid  = threadIdx.x;
    int base = blockIdx.x * 64;

    const float4* Wg4 = (const float4*)W;
    float4* Wl4 = (float4*)Wl;
#pragma unroll
    for (int i = 0; i < 4; ++i) Wl4[tid + i * 256] = Wg4[tid + i * 256];

    if (BF16IN) {
        const unsigned* hb = (const unsigned*)hv;
#pragma unroll
        for (int i = 0; i < 8; ++i) {
            int idx = tid + i * 256;        // uint index in 64x32 tile
            int row = idx >> 5;
            int pc  = idx & 31;
            unsigned v = (base + row < n) ? hb[(size_t)(base + row) * 32 + pc] : 0u;
            hl[row * 65 + 2 * pc]     = blo(v);
            hl[row * 65 + 2 * pc + 1] = bhi(v);
        }
    } else {
        const float4* hg = (const float4*)hv;
#pragma unroll
        for (int i = 0; i < 4; ++i) {
            int idx4 = tid + i * 256;
            int row  = idx4 >> 4;
            int c4   = idx4 & 15;
            float4 v = make_float4(0.f, 0.f, 0.f, 0.f);
            if (base + row < n) v = hg[(size_t)(base + row) * 16 + c4];
            float* dp = &hl[row * 65 + c4 * 4];
            dp[0] = v.x; dp[1] = v.y; dp[2] = v.z; dp[3] = v.w;
        }
    }
    __syncthreads();

    int col4 = tid & 15;
    int rp   = tid >> 4;
    float4 a0 = make_float4(0, 0, 0, 0), a1 = a0, a2 = a0, a3 = a0;
    const float4* WlF4 = (const float4*)Wl;
#pragma unroll 8
    for (int k = 0; k < 64; ++k) {
        float4 w = WlF4[k * 16 + col4];
        float h0 = hl[rp * 65 + k];
        float h1 = hl[(rp + 16) * 65 + k];
        float h2 = hl[(rp + 32) * 65 + k];
        float h3 = hl[(rp + 48) * 65 + k];
        a0.x = fmaf(h0, w.x, a0.x); a0.y = fmaf(h0, w.y, a0.y); a0.z = fmaf(h0, w.z, a0.z); a0.w = fmaf(h0, w.w, a0.w);
        a1.x = fmaf(h1, w.x, a1.x); a1.y = fmaf(h1, w.y, a1.y); a1.z = fmaf(h1, w.z, a1.z); a1.w = fmaf(h1, w.w, a1.w);
        a2.x = fmaf(h2, w.x, a2.x); a2.y = fmaf(h2, w.y, a2.y); a2.z = fmaf(h2, w.z, a2.z); a2.w = fmaf(h2, w.w, a2.w);
        a3.x = fmaf(h3, w.x, a3.x); a3.y = fmaf(h3, w.y, a3.y); a3.z = fmaf(h3, w.z, a3.z); a3.w = fmaf(h3, w.w, a3.w);
    }
    float4 accs[4] = {a0, a1, a2, a3};
#pragma unroll
    for (int r = 0; r < 4; ++r) {
        int row = base + rp + 16 * r;
        if (row < n) {
            float s = dinv[row];
            ((uint2*)hWs)[(size_t)row * 16 + col4] =
                make_uint2(packbf(accs[r].x * s, accs[r].y * s),
                           packbf(accs[r].z * s, accs[r].w * s));
        }
    }
}

// ---------------------------------------------------------------- gather conv (bf16): one 64-lane wave per node
// lanes 0-31 (half=0) process even edges, lanes 32-63 (half=1) odd edges; p = lane&31 = feature pair
template <bool POOL>
__global__ __launch_bounds__(256) void k_gather(const int* __restrict__ rowptr,
                                                const int* __restrict__ csr_src,
                                                const unsigned* __restrict__ hWs,
                                                const float* __restrict__ dinv,
                                                const float* __restrict__ bias,
                                                unsigned* __restrict__ out,
                                                const int* __restrict__ batch,
                                                float* __restrict__ g) {
    int gt   = blockIdx.x * 256 + threadIdx.x;
    int i    = gt >> 6;          // node (one wave)
    int lane = gt & 63;
    int p    = lane & 31;        // feature pair
    int half = lane >> 5;        // 0: even edges, 1: odd edges
    if (i >= NN) return;

    unsigned self = hWs[(size_t)i * 32 + p];
    float acc0 = half ? 0.f : blo(self);
    float acc1 = half ? 0.f : bhi(self);

    int e  = rowptr[i];
    int e1 = rowptr[i + 1];
    // 8 edges per iteration (4 per half)
    for (; e + 8 <= e1; e += 8) {
        int i0 = csr_src[e + half];
        int i1 = csr_src[e + half + 2];
        int i2 = csr_src[e + half + 4];
        int i3 = csr_src[e + half + 6];
        unsigned v0 = hWs[(size_t)i0 * 32 + p];
        unsigned v1 = hWs[(size_t)i1 * 32 + p];
        unsigned v2 = hWs[(size_t)i2 * 32 + p];
        unsigned v3 = hWs[(size_t)i3 * 32 + p];
        acc0 += (blo(v0) + blo(v1)) + (blo(v2) + blo(v3));
        acc1 += (bhi(v0) + bhi(v1)) + (bhi(v2) + bhi(v3));
    }
    for (; e + 2 <= e1; e += 2) {
        unsigned v = hWs[(size_t)csr_src[e + half] * 32 + p];
        acc0 += blo(v); acc1 += bhi(v);
    }
    if (e < e1 && half == 0) {   // odd remainder: half 0 only
        unsigned v = hWs[(size_t)csr_src[e] * 32 + p];
        acc0 += blo(v); acc1 += bhi(v);
    }

    // combine halves: half 1 -> half 0
    acc0 += __shfl_xor(acc0, 32);
    acc1 += __shfl_xor(acc1, 32);

    if (half == 0) {
        float d  = dinv[i];
        float o0 = fmaxf(fmaf(d, acc0, bias[2 * p]), 0.f);
        float o1 = fmaxf(fmaf(d, acc1, bias[2 * p + 1]), 0.f);
        if (POOL) {
            int bg = batch[i];
            unsafeAtomicAdd(&g[(size_t)bg * 64 + 2 * p],     o0);
            unsafeAtomicAdd(&g[(size_t)bg * 64 + 2 * p + 1], o1);
        } else {
            out[(size_t)i * 32 + p] = packbf(o0, o1);
        }
    }
}

// ---------------------------------------------------------------- dense head, one block per graph
__global__ __launch_bounds__(256) void k_dense(const float* __restrict__ g,
                                               const float* __restrict__ Wd1, const float* __restrict__ bd1,
                                               const float* __restrict__ Wd2, const float* __restrict__ bd2,
                                               const float* __restrict__ Wa,  const float* __restrict__ ba,
                                               const float* __restrict__ temp,
                                               const float* __restrict__ mean,
                                               const float* __restrict__ stdv,
                                               float* __restrict__ out) {
    __shared__ float gl[64];
    __shared__ float d1[256];
    __shared__ float d2[128];
    __shared__ float coef[3];
    int tid = threadIdx.x;
    int gid = blockIdx.x;

    if (tid < 64) gl[tid] = fmaxf(g[(size_t)gid * 64 + tid], 0.f);
    __syncthreads();

    float a = bd1[tid];
#pragma unroll 8
    for (int k = 0; k < 64; ++k) a = fmaf(gl[k], Wd1[k * 256 + tid], a);
    d1[tid] = fmaxf(a, 0.f);
    __syncthreads();

    if (tid < 128) {
        float a2 = bd2[tid];
#pragma unroll 8
        for (int k = 0; k < 256; ++k) a2 = fmaf(d1[k], Wd2[k * 128 + tid], a2);
        d2[tid] = fmaxf(a2, 0.f);
    }
    __syncthreads();

    if (tid < 3) {
        float c = ba[tid];
        for (int k = 0; k < 128; ++k) c = fmaf(d2[k], Wa[k * 3 + tid], c);
        coef[tid] = c;
    }
    __syncthreads();

    if (tid == 0) {
        float A = coef[0], B = coef[1], C = coef[2];
        float T = temp[gid];
        float logP = A - B / (T + C);
        out[gid] = (logP - mean[0]) / stdv[0];
    }
}

// ----------------------------------------------------------------
extern "C" void kernel_launch(void* const* d_in, const int* in_sizes, int n_in,
                              void* d_out, int out_size, void* d_ws, size_t ws_size,
                              hipStream_t stream) {
    (void)in_sizes; (void)n_in; (void)out_size; (void)ws_size;
    const float* x     = (const float*)d_in[0];
    const int*   edges = (const int*)d_in[1];
    const int*   batch = (const int*)d_in[2];
    const float* temp  = (const float*)d_in[3];
    const float* mean  = (const float*)d_in[4];
    const float* stdv  = (const float*)d_in[5];
    const float* Wg1 = (const float*)d_in[6];  const float* bg1 = (const float*)d_in[7];
    const float* Wg2 = (const float*)d_in[8];  const float* bg2 = (const float*)d_in[9];
    const float* Wg3 = (const float*)d_in[10]; const float* bg3 = (const float*)d_in[11];
    const float* Wd1 = (const float*)d_in[12]; const float* bd1 = (const float*)d_in[13];
    const float* Wd2 = (const float*)d_in[14]; const float* bd2 = (const float*)d_in[15];
    const float* Wa  = (const float*)d_in[16]; const float* ba  = (const float*)d_in[17];

    // ---- workspace layout
    char* wsb = (char*)d_ws;
    int*      cnt     = (int*)wsb;                       // NN
    int*      rowptr  = cnt + NN;                        // NN+1
    int*      part    = rowptr + NN + 1;                 // NB
    int*      partoff = part + NB;                       // NB
    int*      csr_src = partoff + NB;                    // EE
    float*    dinv    = (float*)(csr_src + EE);          // NN
    float*    gbuf    = dinv + NN;                       // GG*64
    unsigned* bufA    = (unsigned*)(gbuf + (size_t)GG * 64);  // NN*32 (bf16x2)
    unsigned* bufB    = bufA + (size_t)NN * 32;               // NN*32 (bf16x2)

    const int* srcIdx = edges;
    const int* dstIdx = edges + EE;

    // ---- CSR build
    hipMemsetAsync(cnt, 0, NN * sizeof(int), stream);
    k_count<<<(EE + 255) / 256, 256, 0, stream>>>(dstIdx, cnt);
    k_scan1<<<NB, 256, 0, stream>>>(cnt, rowptr, part, dinv);
    k_scan2<<<1, 256, 0, stream>>>(part, partoff, rowptr);
    k_scan3<<<NB, 256, 0, stream>>>(rowptr, partoff);
    k_fill<<<(EE + 255) / 256, 256, 0, stream>>>(srcIdx, dstIdx, rowptr, cnt, csr_src);

    const int GEMM_BLOCKS = (NN + 63) / 64;
    const int GATH_BLOCKS = (NN * 64 + 255) / 256;

    // ---- layer 1: x(fp32) -> bufB(hWs bf16) -> bufA(bf16)
    k_gemm<false><<<GEMM_BLOCKS, 256, 0, stream>>>(x, Wg1, dinv, bufB, NN);
    k_gather<false><<<GATH_BLOCKS, 256, 0, stream>>>(rowptr, csr_src, bufB, dinv, bg1, bufA, batch, gbuf);

    // ---- layer 2: bufA -> bufB -> bufA
    k_gemm<true><<<GEMM_BLOCKS, 256, 0, stream>>>(bufA, Wg2, dinv, bufB, NN);
    k_gather<false><<<GATH_BLOCKS, 256, 0, stream>>>(rowptr, csr_src, bufB, dinv, bg2, bufA, batch, gbuf);

    // ---- layer 3: bufA -> bufB -> pool into gbuf (no feature write)
    hipMemsetAsync(gbuf, 0, (size_t)GG * 64 * sizeof(float), stream);
    k_gemm<true><<<GEMM_BLOCKS, 256, 0, stream>>>(bufA, Wg3, dinv, bufB, NN);
    k_gather<true><<<GATH_BLOCKS, 256, 0, stream>>>(rowptr, csr_src, bufB, dinv, bg3, bufA, batch, gbuf);

    // ---- head
    k_dense<<<GG, 256, 0, stream>>>(gbuf, Wd1, bd1, Wd2, bd2, Wa, ba, temp, mean, stdv, (float*)d_out);
}